// Round 6
// baseline (286.987 us; speedup 1.0000x reference)
//
#include <hip/hip_runtime.h>

#define SEQ   1024
#define EMBED 1024
#define NH    16
#define HD    64
#define NB    16

typedef float facc4 __attribute__((ext_vector_type(4)));
typedef float facc16 __attribute__((ext_vector_type(16)));
typedef short frag8 __attribute__((ext_vector_type(8)));
typedef short sv4 __attribute__((ext_vector_type(4)));

__device__ __forceinline__ unsigned short f2bf(float f) {
  union { float f; unsigned int u; } c; c.f = f;
  unsigned int u = c.u;
  u += 0x7FFFu + ((u >> 16) & 1u);   // round-to-nearest-even
  return (unsigned short)(u >> 16);
}

__device__ __forceinline__ unsigned int pk_bf16(float lo, float hi) {
  unsigned int r;
  asm("v_cvt_pk_bf16_f32 %0, %1, %2" : "=v"(r) : "v"(lo), "v"(hi));
  return r;
}

__device__ __forceinline__ void gl_lds16(const void* g, void* l) {
  __builtin_amdgcn_global_load_lds(
      (const __attribute__((address_space(1))) unsigned int*)g,
      (__attribute__((address_space(3))) unsigned int*)l, 16, 0, 0);
}

// ---------------- convert x (f32 -> bf16), 8 elems/thread/iter ----------------
__global__ __launch_bounds__(256) void convert_x_kernel(
    const float* __restrict__ x, unsigned short* __restrict__ xb, int n8) {
  int stride = gridDim.x * blockDim.x;
  for (int i = blockIdx.x * blockDim.x + threadIdx.x; i < n8; i += stride) {
    const float4* src = (const float4*)(x + (size_t)i * 8);
    float4 v0 = src[0], v1 = src[1];
    frag8 o;
    o[0] = f2bf(v0.x); o[1] = f2bf(v0.y); o[2] = f2bf(v0.z); o[3] = f2bf(v0.w);
    o[4] = f2bf(v1.x); o[5] = f2bf(v1.y); o[6] = f2bf(v1.z); o[7] = f2bf(v1.w);
    *(frag8*)(xb + (size_t)i * 8) = o;
  }
}

// ------------- transpose + convert W [1024x1024] f32 -> Wt bf16 ---------------
__global__ __launch_bounds__(256) void transpose_w_kernel(
    const float* W0, const float* W1, const float* W2, const float* W3,
    unsigned short* T0, unsigned short* T1, unsigned short* T2, unsigned short* T3) {
  __shared__ float tw[64][65];
  const float* W; unsigned short* T;
  switch (blockIdx.z) {
    case 0: W = W0; T = T0; break;
    case 1: W = W1; T = T1; break;
    case 2: W = W2; T = T2; break;
    default: W = W3; T = T3; break;
  }
  int k0 = blockIdx.y * 64, n0 = blockIdx.x * 64;
  int t = threadIdx.x;
#pragma unroll
  for (int rep = 0; rep < 4; ++rep) {
    int c = rep * 256 + t;          // 1024 float4 chunks
    int row = c >> 4, ch = c & 15;
    float4 v = *(const float4*)(W + (size_t)(k0 + row) * 1024 + n0 + ch * 4);
    tw[row][ch * 4 + 0] = v.x; tw[row][ch * 4 + 1] = v.y;
    tw[row][ch * 4 + 2] = v.z; tw[row][ch * 4 + 3] = v.w;
  }
  __syncthreads();
#pragma unroll
  for (int rep = 0; rep < 2; ++rep) {
    int c = rep * 256 + t;          // 512 short8 chunks
    int nrow = c >> 3, ch = c & 7;
    frag8 o;
#pragma unroll
    for (int i = 0; i < 8; ++i) o[i] = (short)f2bf(tw[ch * 8 + i][nrow]);
    *(frag8*)(T + (size_t)(n0 + nrow) * 1024 + k0 + ch * 8) = o;
  }
}

// ============ GEMM 256x256, BK=64, 8 waves, m201-style 4-phase/K-tile ========
// Per K-tile u (buf p=u&1), phases:
//  P0: read A[mi0-3]x2ks(8)+B[nj0-1]x2ks(4); stage A-h0(u+1); bar; lgkm0; 16 MFMA; bar
//  P1: read B[nj2-3](4);                    stage A-h1(u+1); bar; lgkm0; 16 MFMA; bar
//  P2: read A[mi4-7](8);                    stage B-h0(u+2); bar; lgkm0; 16 MFMA; bar
//  P3: (no reads)                           stage B-h1(u+2); bar; 16 MFMA;
//      vmcnt(4) [u==14: 0] ; bar            <- vouch-then-barrier for next reads
// Stage-target freedom: A-halves last read P2, staged P0/P1 next tile (2+ barriers);
// B-halves last read P1, staged P2/P3 same tile. vmcnt(4) leaves B(u+2) in flight.
// LDS XOR-swizzle (chunk^=row&7) via pre-swizzled global source; conflict-free.
template <int MODE>
__global__ __launch_bounds__(512, 2) void gemm256(
    const unsigned short* __restrict__ A, const unsigned short* __restrict__ Bt,
    unsigned short* __restrict__ qo, unsigned short* __restrict__ ko,
    unsigned short* __restrict__ vto, float* __restrict__ fo, int N) {
  __shared__ unsigned short a_s[2][256 * 64];
  __shared__ unsigned short b_s[2][256 * 64];
  const int tid = threadIdx.x;
  const int w = tid >> 6, l = tid & 63;
  const int l15 = l & 15, l4 = l >> 4;        // quarter index 0..3
  const int wr = w >> 2, wc = w & 3;          // 2 x 4 wave grid, tile 128x64

  const int bid = blockIdx.x;
  const int xcd = bid & 7, j = bid >> 3;      // 8 m-tiles per XCD, n-outer
  const int mt = xcd * 8 + (j & 7), nt = j >> 3;
  const int m0 = mt << 8, n0 = nt << 8;

  const int ldrow = l >> 3;                               // 0..7
  const int swz8 = ((l & 7) ^ (ldrow & 7)) << 3;          // swizzled src chunk
  const unsigned short* Ab = A + (size_t)m0 * 1024;
  const unsigned short* Bb = Bt + (size_t)n0 * 1024;

  facc4 acc[8][4];
#pragma unroll
  for (int mi = 0; mi < 8; ++mi)
#pragma unroll
    for (int nj = 0; nj < 4; ++nj)
#pragma unroll
      for (int r = 0; r < 4; ++r) acc[mi][nj][r] = 0.f;

  // stage ONE 128-row half of A or B: 2 gl_lds per thread (16 KB per block)
  auto STAGE_A = [&](int buf, int half, int kt) {
#pragma unroll
    for (int i = 0; i < 2; ++i) {
      const int c = (w << 1) + i;             // 0..15
      const int rb = (half << 7) + (c << 3);
      gl_lds16(Ab + (size_t)kt * 64 + (size_t)(rb + ldrow) * 1024 + swz8,
               &a_s[buf][rb << 6]);
    }
  };
  auto STAGE_B = [&](int buf, int half, int kt) {
#pragma unroll
    for (int i = 0; i < 2; ++i) {
      const int c = (w << 1) + i;
      const int rb = (half << 7) + (c << 3);
      gl_lds16(Bb + (size_t)kt * 64 + (size_t)(rb + ldrow) * 1024 + swz8,
               &b_s[buf][rb << 6]);
    }
  };

  // prologue: A(0), B(0), B(1); vouch A(0)+B(0), leave B(1) in flight
  STAGE_A(0, 0, 0); STAGE_A(0, 1, 0);
  STAGE_B(0, 0, 0); STAGE_B(0, 1, 0);
  STAGE_B(1, 0, 1); STAGE_B(1, 1, 1);
  asm volatile("s_waitcnt vmcnt(4)" ::: "memory");
  __builtin_amdgcn_s_barrier();
  __builtin_amdgcn_sched_barrier(0);

  const int rowA = (wr << 7) + l15;   // + mi*16
  const int rowB = (wc << 6) + l15;   // + nj*16

  frag8 aq[4][2], bq0[2][2], bq1[2][2];

  for (int u = 0; u < 16; ++u) {
    const int p = u & 1;
    const unsigned short* ap = a_s[p];
    const unsigned short* bp = b_s[p];

    // ================= P0: A[mi0-3], B[nj0-1] -> Q(A0,B0) =================
#pragma unroll
    for (int mi = 0; mi < 4; ++mi) {
      const int r = rowA + (mi << 4);
#pragma unroll
      for (int ks = 0; ks < 2; ++ks)
        aq[mi][ks] = *(const frag8*)(ap + (r << 6) + ((((ks << 2) | l4) ^ (r & 7)) << 3));
    }
#pragma unroll
    for (int nj = 0; nj < 2; ++nj) {
      const int r = rowB + (nj << 4);
#pragma unroll
      for (int ks = 0; ks < 2; ++ks)
        bq0[nj][ks] = *(const frag8*)(bp + (r << 6) + ((((ks << 2) | l4) ^ (r & 7)) << 3));
    }
    if (u + 1 < 16) STAGE_A(p ^ 1, 0, u + 1);
    asm volatile("s_waitcnt lgkmcnt(8)" ::: "memory");
    __builtin_amdgcn_s_barrier();
    asm volatile("s_waitcnt lgkmcnt(0)" ::: "memory");
    __builtin_amdgcn_sched_barrier(0);
    __builtin_amdgcn_s_setprio(1);
#pragma unroll
    for (int ks = 0; ks < 2; ++ks)
#pragma unroll
      for (int mi = 0; mi < 4; ++mi)
#pragma unroll
        for (int nj = 0; nj < 2; ++nj)
          acc[mi][nj] = __builtin_amdgcn_mfma_f32_16x16x32_bf16(
              aq[mi][ks], bq0[nj][ks], acc[mi][nj], 0, 0, 0);
    __builtin_amdgcn_s_setprio(0);
    __builtin_amdgcn_s_barrier();

    // ================= P1: B[nj2-3] -> Q(A0,B1) =================
#pragma unroll
    for (int nj = 0; nj < 2; ++nj) {
      const int r = rowB + ((nj + 2) << 4);
#pragma unroll
      for (int ks = 0; ks < 2; ++ks)
        bq1[nj][ks] = *(const frag8*)(bp + (r << 6) + ((((ks << 2) | l4) ^ (r & 7)) << 3));
    }
    if (u + 1 < 16) STAGE_A(p ^ 1, 1, u + 1);
    __builtin_amdgcn_s_barrier();
    asm volatile("s_waitcnt lgkmcnt(0)" ::: "memory");
    __builtin_amdgcn_sched_barrier(0);
    __builtin_amdgcn_s_setprio(1);
#pragma unroll
    for (int ks = 0; ks < 2; ++ks)
#pragma unroll
      for (int mi = 0; mi < 4; ++mi)
#pragma unroll
        for (int nj = 0; nj < 2; ++nj)
          acc[mi][nj + 2] = __builtin_amdgcn_mfma_f32_16x16x32_bf16(
              aq[mi][ks], bq1[nj][ks], acc[mi][nj + 2], 0, 0, 0);
    __builtin_amdgcn_s_setprio(0);
    __builtin_amdgcn_s_barrier();

    // ================= P2: A[mi4-7] -> Q(A1,B1) =================
#pragma unroll
    for (int mi = 0; mi < 4; ++mi) {
      const int r = rowA + ((mi + 4) << 4);
#pragma unroll
      for (int ks = 0; ks < 2; ++ks)
        aq[mi][ks] = *(const frag8*)(ap + (r << 6) + ((((ks << 2) | l4) ^ (r & 7)) << 3));
    }
    if (u + 2 < 16) STAGE_B(p, 0, u + 2);
    __builtin_amdgcn_s_barrier();
    asm volatile("s_waitcnt lgkmcnt(0)" ::: "memory");
    __builtin_amdgcn_sched_barrier(0);
    __builtin_amdgcn_s_setprio(1);
#pragma unroll
    for (int ks = 0; ks < 2; ++ks)
#pragma unroll
      for (int mi = 0; mi < 4; ++mi)
#pragma unroll
        for (int nj = 0; nj < 2; ++nj)
          acc[mi + 4][nj + 2] = __builtin_amdgcn_mfma_f32_16x16x32_bf16(
              aq[mi][ks], bq1[nj][ks], acc[mi + 4][nj + 2], 0, 0, 0);
    __builtin_amdgcn_s_setprio(0);
    __builtin_amdgcn_s_barrier();

    // ================= P3: (no reads) -> Q(A1,B0) =================
    if (u + 2 < 16) STAGE_B(p, 1, u + 2);
    __builtin_amdgcn_s_barrier();
    __builtin_amdgcn_s_setprio(1);
#pragma unroll
    for (int ks = 0; ks < 2; ++ks)
#pragma unroll
      for (int mi = 0; mi < 4; ++mi)
#pragma unroll
        for (int nj = 0; nj < 2; ++nj)
          acc[mi + 4][nj] = __builtin_amdgcn_mfma_f32_16x16x32_bf16(
              aq[mi][ks], bq0[nj][ks], acc[mi + 4][nj], 0, 0, 0);
    __builtin_amdgcn_s_setprio(0);
    // vouch-then-barrier: next phase's cross-wave reads need A(u+1) landed
    if (u < 14)       asm volatile("s_waitcnt vmcnt(4)" ::: "memory");
    else if (u == 14) asm volatile("s_waitcnt vmcnt(0)" ::: "memory");
    if (u < 15) {
      __builtin_amdgcn_s_barrier();
      __builtin_amdgcn_sched_barrier(0);
    }
  }

  // ---- epilogue (16x16 C layout: col = l&15, row = l4*4 + r) ----
  const int m_base = m0 + (wr << 7);
  if (MODE == 0) {
    const int bb16 = (m_base >> 10) << 4;               // batch*16
#pragma unroll
    for (int nj = 0; nj < 4; ++nj) {
      const int n = n0 + (wc << 6) + (nj << 4) + l15;
      const int proj = n >> 10, rem = n & 1023;
      const int h = rem >> 6, d = rem & 63;
      const size_t bh16 = ((size_t)(bb16 + h)) << 16;   // *SEQ*64
      if (proj == 2) {
        // V: write transposed [bh][d][s]; lane holds 4 consecutive s -> sv4
#pragma unroll
        for (int mi = 0; mi < 8; ++mi) {
          const int s0 = (m_base + (mi << 4) + (l4 << 2)) & 1023;
          sv4 pv;
#pragma unroll
          for (int rr = 0; rr < 4; ++rr) pv[rr] = (short)f2bf(acc[mi][nj][rr]);
          *(sv4*)(vto + bh16 + ((size_t)d << 10) + s0) = pv;
        }
      } else {
        unsigned short* dst = (proj == 0) ? qo : ko;
#pragma unroll
        for (int mi = 0; mi < 8; ++mi)
#pragma unroll
          for (int rr = 0; rr < 4; ++rr) {
            const int s = (m_base + (mi << 4) + (l4 << 2) + rr) & 1023;
            dst[bh16 + (size_t)s * 64 + d] = f2bf(acc[mi][nj][rr]);
          }
      }
    }
  } else {
#pragma unroll
    for (int nj = 0; nj < 4; ++nj) {
      const int n = n0 + (wc << 6) + (nj << 4) + l15;
#pragma unroll
      for (int mi = 0; mi < 8; ++mi)
#pragma unroll
        for (int rr = 0; rr < 4; ++rr) {
          const int m = m_base + (mi << 4) + (l4 << 2) + rr;
          fo[(size_t)m * N + n] = acc[mi][nj][rr];
        }
    }
  }
}

// ------------- flash attention, swapped-QK^T 32x32, counted-vmcnt dbuf -------
// (unchanged from round 4)
__global__ __launch_bounds__(256, 4) void attn_kernel(
    const unsigned short* __restrict__ q, const unsigned short* __restrict__ k,
    const unsigned short* __restrict__ vt, const float* __restrict__ rel_bias,
    unsigned short* __restrict__ ao) {
  __shared__ unsigned short smem[16384];      // K dbuf [2][4096] | V dbuf [2][4096]
  __shared__ float rb_s[63];
  unsigned short* k_s = smem;                 // 2 x 8 KiB
  unsigned short* v_s = smem + 8192;          // 2 x 8 KiB

  const int bid = blockIdx.x;
  const int xcd = bid & 7, jj = bid >> 3;
  const int bh = xcd * 32 + (jj >> 3), qt = jj & 7;   // 8 q-blocks of a bh -> one XCD
  const int b = bh >> 4, h = bh & 15;
  const int t = threadIdx.x, w = t >> 6, l = t & 63;
  const int l31 = l & 31, hi = l >> 5;

  if (t < 63) rb_s[t] = rel_bias[h * 63 + t] * 1.44269504f;  // pre-scale log2e

  const unsigned short* qg = q + (size_t)bh * (SEQ * 64);
  const unsigned short* kg = k + (size_t)bh * (SEQ * 64);
  const unsigned short* vg = vt + (size_t)bh * (64 * SEQ);

  const int q0 = qt * 128 + w * 32;  // wave's q base (multiple of 32)
  const int qr = q0 >> 5;            // board row of all 32 queries' base

  // Q as B-operand frags: lane holds col q = q0+l31, d-slice s: d = s*16+hi*8+j
  frag8 qf[4];
#pragma unroll
  for (int s = 0; s < 4; ++s)
    qf[s] = *(const frag8*)(qg + (size_t)(q0 + l31) * 64 + s * 16 + hi * 8);

  // stage kt into buffer (4 gl_lds per wave)
  auto STAGE = [&](int buf, int kt) {
#pragma unroll
    for (int i = 0; i < 2; ++i) {
      const int c = i * 256 + t;
      const int row = c >> 3, ch = c & 7;
      const int sw = (ch ^ (row & 7)) << 3;          // pre-swizzled src (shorts)
      const int base = ((i * 256 + w * 64) << 3) + buf * 4096;  // wave-uniform dest
      gl_lds16(kg + (size_t)(kt * 64 + row) * 64 + sw, k_s + base);
      gl_lds16(vg + (size_t)row * SEQ + kt * 64 + sw, v_s + base);
    }
  };
  STAGE(0, 0);

  asm volatile("s_waitcnt lgkmcnt(0)" ::: "memory");  // rb_s write landed
  __builtin_amdgcn_s_barrier();
  __builtin_amdgcn_sched_barrier(0);

  // rel_x bias per acc register r: kc = (r&3)+8*(r>>2)+4*hi, qc = l31
  float bx[16];
#pragma unroll
  for (int r = 0; r < 16; ++r) {
    const int kc = (r & 3) + 8 * (r >> 2) + 4 * hi;
    bx[r] = rb_s[kc - l31 + 31];
  }

  float m_run = -1e30f, lsum = 0.f;
  facc16 o0, o1;
#pragma unroll
  for (int i = 0; i < 16; ++i) { o0[i] = 0.f; o1[i] = 0.f; }

  const float C1 = 0.125f * 1.44269504f;  // score scale in exp2 domain

  for (int kt = 0; kt < 16; ++kt) {
    const int p = kt & 1;
    if (kt < 15) {
      STAGE(p ^ 1, kt + 1);
      asm volatile("s_waitcnt vmcnt(4)" ::: "memory");  // kt landed, kt+1 in flight
    } else {
      asm volatile("s_waitcnt vmcnt(0)" ::: "memory");
    }
    __builtin_amdgcn_s_barrier();
    __builtin_amdgcn_sched_barrier(0);

    const char* kp = (const char*)(k_s + p * 4096);
    const char* vp = (const char*)(v_s + p * 4096);

    // ---- QK^T: S^T[key, q] per 32-key subtile ----
    facc16 sa[2];
    __builtin_amdgcn_s_setprio(1);
#pragma unroll
    for (int st = 0; st < 2; ++st) {
      facc16 z;
#pragma unroll
      for (int i = 0; i < 16; ++i) z[i] = 0.f;
#pragma unroll
      for (int s = 0; s < 4; ++s) {
        const int row = st * 32 + l31;
        const int byte_off = row * 128 + (((s * 2 + hi) ^ (row & 7)) << 4);
        frag8 kf = *(const frag8*)(kp + byte_off);
        z = __builtin_amdgcn_mfma_f32_32x32x16_bf16(kf, qf[s], z, 0, 0, 0);
      }
      sa[st] = z;
    }
    __builtin_amdgcn_s_setprio(0);

    // ---- bias + online softmax (exp2 domain) ----
    const float by0 = rb_s[kt * 2 + 0 - qr + 31];
    const float by1 = rb_s[kt * 2 + 1 - qr + 31];
    float sc0[16], sc1[16];
#pragma unroll
    for (int r = 0; r < 16; ++r) {
      sc0[r] = __builtin_fmaf(sa[0][r], C1, bx[r]);
      sc1[r] = __builtin_fmaf(sa[1][r], C1, bx[r]);
    }
    float m0 = sc0[0], m1 = sc1[0];
#pragma unroll
    for (int r = 1; r < 16; ++r) { m0 = fmaxf(m0, sc0[r]); m1 = fmaxf(m1, sc1[r]); }
    float tm = fmaxf(m0 + by0, m1 + by1);
    tm = fmaxf(tm, __shfl_xor(tm, 32));
    if (!__all(tm <= m_run + 8.f)) {         // defer-max (T13)
      const float mn = fmaxf(m_run, tm);
      const float corr = __builtin_amdgcn_exp2f(m_run - mn);
      lsum *= corr;
#pragma unroll
      for (int i = 0; i < 16; ++i) { o0[i] *= corr; o1[i] *= corr; }
      m_run = mn;
    }
    const float mb0 = m_run - by0, mb1 = m_run - by1;
    float p0[16], p1[16];
    float ps = 0.f;
#pragma unroll
    for (int r = 0; r < 16; ++r) {
      p0[r] = __builtin_amdgcn_exp2f(sc0[r] - mb0);
      p1[r] = __builtin_amdgcn_exp2f(sc1[r] - mb1);
      ps += p0[r] + p1[r];
    }
    ps += __shfl_xor(ps, 32);
    lsum += ps;

    // ---- repack P -> bf16 B-operand frags (cvt_pk + xor-32 exchange) ----
    unsigned int fw[4][4];
#pragma unroll
    for (int ks = 0; ks < 4; ++ks) {
      const float* pp = (ks < 2) ? p0 : p1;
      const int R0 = (ks & 1) * 8;       // reg base for dest hi=0
      const int R1 = R0 + 4;             // reg base for dest hi=1
      const unsigned int w00 = pk_bf16(pp[R0 + 0], pp[R0 + 1]);
      const unsigned int w01 = pk_bf16(pp[R0 + 2], pp[R0 + 3]);
      const unsigned int w10 = pk_bf16(pp[R1 + 0], pp[R1 + 1]);
      const unsigned int w11 = pk_bf16(pp[R1 + 2], pp[R1 + 3]);
      const unsigned int s0 = hi ? w00 : w10;   // what partner needs
      const unsigned int s1 = hi ? w01 : w11;
      const unsigned int r0 = __shfl_xor((int)s0, 32);
      const unsigned int r1 = __shfl_xor((int)s1, 32);
      fw[ks][0] = hi ? r0 : w00;
      fw[ks][1] = hi ? r1 : w01;
      fw[ks][2] = hi ? w10 : r0;
      fw[ks][3] = hi ? w11 : r1;
    }

    // ---- PV: O^T[d, q] += V^T · P^T ----
    __builtin_amdgcn_s_setprio(1);
#pragma unroll
    for (int ks = 0; ks < 4; ++ks) {
      frag8 pb;
      {
        union { unsigned int u[4]; frag8 f; } cv;
        cv.u[0] = fw[ks][0]; cv.u[1] = fw[ks][1];
        cv.u[2] = fw[ks][2]; cv.u[3] = fw[ks][3];
        pb = cv.f;
      }
      {
        const int row = l31;  // dt = 0
        const int byte_off = row * 128 + (((ks * 2 + hi) ^ (row & 7)) << 4);
        frag8 vf = *(const frag8*)(vp + byte_off);
        o0 = __builtin_amdgcn_mfma_f32_32x32x16_bf16(vf, pb, o0, 0, 0, 0);
      }
      {
        const int row = 32 + l31;  // dt = 1
        const int byte_off = row * 128 + (((ks * 2 + hi) ^ (row & 7)) << 4);
        frag8 vf = *(const frag8*)(vp + byte_off);
        o1 = __builtin_amdgcn_mfma_f32_32x32x16_bf16(vf, pb, o1, 0, 0, 0);
      }
    }
    __builtin_amdgcn_s_setprio(0);

    // all LDS reads of buf p consumed; free it for stage(kt+2)
    asm volatile("s_waitcnt lgkmcnt(0)" ::: "memory");
    __builtin_amdgcn_s_barrier();
    __builtin_amdgcn_sched_barrier(0);
  }

  // ---- epilogue: divide, transpose via wave-private LDS (aliased), store ----
  const float inv = __builtin_amdgcn_rcpf(lsum);
  unsigned short (*os)[72] = (unsigned short (*)[72])(smem + w * (32 * 72));
#pragma unroll
  for (int dt = 0; dt < 2; ++dt) {
#pragma unroll
    for (int r = 0; r < 16; r += 2) {
      const int d = (r & 3) + 8 * (r >> 2) + 4 * hi + 32 * dt;
      const float e0 = (dt ? o1[r] : o0[r]) * inv;
      const float e1 = (dt ? o1[r + 1] : o0[r + 1]) * inv;
      *(unsigned int*)&os[l31][d] = pk_bf16(e0, e1);
    }
  }
  asm volatile("s_waitcnt lgkmcnt(0)" ::: "memory");  // wave-private region
  __builtin_amdgcn_sched_barrier(0);
#pragma unroll
  for (int i = 0; i < 4; ++i) {
    const int c = i * 64 + l;
    const int qrow = c >> 3, ch = c & 7;
    frag8 ov = *(const frag8*)(&os[qrow][ch * 8]);
    *(frag8*)(ao + ((size_t)(b * SEQ + q0 + qrow) * EMBED + h * 64 + ch * 8)) = ov;
  }
}

// ------------------------------- launcher ------------------------------------
extern "C" void kernel_launch(void* const* d_in, const int* in_sizes, int n_in,
                              void* d_out, int out_size, void* d_ws, size_t ws_size,
                              hipStream_t stream) {
  (void)in_sizes; (void)n_in; (void)out_size; (void)ws_size;
  const float* x  = (const float*)d_in[0];
  const float* Wq = (const float*)d_in[1];
  const float* Wk = (const float*)d_in[2];
  const float* Wv = (const float*)d_in[3];
  const float* Wo = (const float*)d_in[4];
  const float* rb = (const float*)d_in[5];
  float* out = (float*)d_out;

  unsigned short* xb  = (unsigned short*)d_ws;      // 16M elems
  unsigned short* wtq = xb + 16777216;              // 1M each, q|k|v contiguous
  unsigned short* wtk = wtq + 1048576;
  unsigned short* wtv = wtk + 1048576;
  unsigned short* wto = wtv + 1048576;
  unsigned short* qb  = wto + 1048576;              // 16M each
  unsigned short* kb  = qb + 16777216;
  unsigned short* aob = kb + 16777216;
  unsigned short* vtb = aob + 16777216;

  convert_x_kernel<<<4096, 256, 0, stream>>>(x, xb, 16777216 / 8);
  transpose_w_kernel<<<dim3(16, 16, 4), 256, 0, stream>>>(
      Wq, Wk, Wv, Wo, wtq, wtk, wtv, wto);
  gemm256<0><<<768, 512, 0, stream>>>(
      xb, wtq, qb, kb, vtb, nullptr, 3072);
  attn_kernel<<<2048, 256, 0, stream>>>(qb, kb, vtb, rb, aob);
  gemm256<1><<<256, 512, 0, stream>>>(
      aob, wto, nullptr, nullptr, nullptr, out, 1024);
}

// Round 7
// 271.648 us; speedup vs baseline: 1.0565x; 1.0565x over previous
//
#include <hip/hip_runtime.h>

#define SEQ   1024
#define EMBED 1024
#define NH    16
#define HD    64
#define NB    16

typedef float facc4 __attribute__((ext_vector_type(4)));
typedef float facc16 __attribute__((ext_vector_type(16)));
typedef short frag8 __attribute__((ext_vector_type(8)));
typedef short sv4 __attribute__((ext_vector_type(4)));

__device__ __forceinline__ unsigned short f2bf(float f) {
  union { float f; unsigned int u; } c; c.f = f;
  unsigned int u = c.u;
  u += 0x7FFFu + ((u >> 16) & 1u);   // round-to-nearest-even
  return (unsigned short)(u >> 16);
}

__device__ __forceinline__ unsigned int pk_bf16(float lo, float hi) {
  unsigned int r;
  asm("v_cvt_pk_bf16_f32 %0, %1, %2" : "=v"(r) : "v"(lo), "v"(hi));
  return r;
}

__device__ __forceinline__ void gl_lds16(const void* g, void* l) {
  __builtin_amdgcn_global_load_lds(
      (const __attribute__((address_space(1))) unsigned int*)g,
      (__attribute__((address_space(3))) unsigned int*)l, 16, 0, 0);
}

// ---------------- convert x (f32 -> bf16), 8 elems/thread/iter ----------------
__global__ __launch_bounds__(256) void convert_x_kernel(
    const float* __restrict__ x, unsigned short* __restrict__ xb, int n8) {
  int stride = gridDim.x * blockDim.x;
  for (int i = blockIdx.x * blockDim.x + threadIdx.x; i < n8; i += stride) {
    const float4* src = (const float4*)(x + (size_t)i * 8);
    float4 v0 = src[0], v1 = src[1];
    frag8 o;
    o[0] = f2bf(v0.x); o[1] = f2bf(v0.y); o[2] = f2bf(v0.z); o[3] = f2bf(v0.w);
    o[4] = f2bf(v1.x); o[5] = f2bf(v1.y); o[6] = f2bf(v1.z); o[7] = f2bf(v1.w);
    *(frag8*)(xb + (size_t)i * 8) = o;
  }
}

// ------------- transpose + convert W [1024x1024] f32 -> Wt bf16 ---------------
__global__ __launch_bounds__(256) void transpose_w_kernel(
    const float* W0, const float* W1, const float* W2, const float* W3,
    unsigned short* T0, unsigned short* T1, unsigned short* T2, unsigned short* T3) {
  __shared__ float tw[64][65];
  const float* W; unsigned short* T;
  switch (blockIdx.z) {
    case 0: W = W0; T = T0; break;
    case 1: W = W1; T = T1; break;
    case 2: W = W2; T = T2; break;
    default: W = W3; T = T3; break;
  }
  int k0 = blockIdx.y * 64, n0 = blockIdx.x * 64;
  int t = threadIdx.x;
#pragma unroll
  for (int rep = 0; rep < 4; ++rep) {
    int c = rep * 256 + t;          // 1024 float4 chunks
    int row = c >> 4, ch = c & 15;
    float4 v = *(const float4*)(W + (size_t)(k0 + row) * 1024 + n0 + ch * 4);
    tw[row][ch * 4 + 0] = v.x; tw[row][ch * 4 + 1] = v.y;
    tw[row][ch * 4 + 2] = v.z; tw[row][ch * 4 + 3] = v.w;
  }
  __syncthreads();
#pragma unroll
  for (int rep = 0; rep < 2; ++rep) {
    int c = rep * 256 + t;          // 512 short8 chunks
    int nrow = c >> 3, ch = c & 7;
    frag8 o;
#pragma unroll
    for (int i = 0; i < 8; ++i) o[i] = (short)f2bf(tw[ch * 8 + i][nrow]);
    *(frag8*)(T + (size_t)(n0 + nrow) * 1024 + k0 + ch * 8) = o;
  }
}

// ============ GEMM 256x256, BK=64, 8 waves, 2-phase counted-vmcnt ============
// Round-5 skeleton (best measured), WITHOUT sched_barrier(0) order-pins:
// per K-tile: reads slice0 (12 b128) -> 32 MFMA -> reads slice1 (12) ->
// lgkmcnt(0)+barrier (buf free) -> STAGE(t+2) -> 32 MFMA -> vmcnt(8)+barrier.
// Waitcnts keep "memory" clobber (orders all memory ops); register-only ops
// may cross freely (compiler dataflow waits protect them) — rule 18 applies
// only to inline-asm ds_read, none here.
template <int MODE>
__global__ __launch_bounds__(512, 2) void gemm256(
    const unsigned short* __restrict__ A, const unsigned short* __restrict__ Bt,
    unsigned short* __restrict__ qo, unsigned short* __restrict__ ko,
    unsigned short* __restrict__ vto, float* __restrict__ fo, int N) {
  __shared__ unsigned short a_s[2][256 * 64];
  __shared__ unsigned short b_s[2][256 * 64];
  const int tid = threadIdx.x;
  const int w = tid >> 6, l = tid & 63;
  const int l15 = l & 15, l4 = l >> 4;        // quarter index 0..3
  const int wr = w >> 2, wc = w & 3;          // 2 x 4 wave grid, tile 128x64

  const int bid = blockIdx.x;
  const int xcd = bid & 7, j = bid >> 3;      // 8 m-tiles per XCD, n-outer
  const int mt = xcd * 8 + (j & 7), nt = j >> 3;
  const int m0 = mt << 8, n0 = nt << 8;

  const int ldrow = l >> 3;                               // 0..7
  const int swz8 = ((l & 7) ^ (ldrow & 7)) << 3;          // swizzled src chunk
  const unsigned short* Ab = A + (size_t)m0 * 1024;
  const unsigned short* Bb = Bt + (size_t)n0 * 1024;

  facc4 acc[8][4];
#pragma unroll
  for (int mi = 0; mi < 8; ++mi)
#pragma unroll
    for (int nj = 0; nj < 4; ++nj)
#pragma unroll
      for (int r = 0; r < 4; ++r) acc[mi][nj][r] = 0.f;

  auto STAGE = [&](int buf, int kt) {
#pragma unroll
    for (int i = 0; i < 4; ++i) {
      const int c = (w << 2) + i;             // 8 rows per chunk-instr
      gl_lds16(Ab + (size_t)kt * 64 + (size_t)((c << 3) + ldrow) * 1024 + swz8,
               &a_s[buf][c << 9]);
      gl_lds16(Bb + (size_t)kt * 64 + (size_t)((c << 3) + ldrow) * 1024 + swz8,
               &b_s[buf][c << 9]);
    }
  };

  STAGE(0, 0);
  STAGE(1, 1);
  asm volatile("s_waitcnt vmcnt(8)" ::: "memory");   // K-tile 0 landed
  __builtin_amdgcn_s_barrier();

  const int rowA = (wr << 7) + l15;   // + mi*16
  const int rowB = (wc << 6) + l15;   // + nj*16

  for (int t = 0; t < 16; ++t) {
    const int cur = t & 1;
    const unsigned short* ap = a_s[cur];
    const unsigned short* bp = b_s[cur];
    frag8 af[8], bf[4];

    // ---- k-slice 0: reads (chunk cc = l4, XOR row&7) + 32 MFMA ----
#pragma unroll
    for (int mi = 0; mi < 8; ++mi) {
      const int r = rowA + (mi << 4);
      af[mi] = *(const frag8*)(ap + (r << 6) + ((l4 ^ (r & 7)) << 3));
    }
#pragma unroll
    for (int nj = 0; nj < 4; ++nj) {
      const int r = rowB + (nj << 4);
      bf[nj] = *(const frag8*)(bp + (r << 6) + ((l4 ^ (r & 7)) << 3));
    }
    __builtin_amdgcn_s_setprio(1);
#pragma unroll
    for (int mi = 0; mi < 8; ++mi)
#pragma unroll
      for (int nj = 0; nj < 4; ++nj)
        acc[mi][nj] = __builtin_amdgcn_mfma_f32_16x16x32_bf16(
            af[mi], bf[nj], acc[mi][nj], 0, 0, 0);
    __builtin_amdgcn_s_setprio(0);

    // ---- k-slice 1 reads (chunk cc = 4 + l4) ----
    frag8 ag[8], bg[4];
#pragma unroll
    for (int mi = 0; mi < 8; ++mi) {
      const int r = rowA + (mi << 4);
      ag[mi] = *(const frag8*)(ap + (r << 6) + (((4 + l4) ^ (r & 7)) << 3));
    }
#pragma unroll
    for (int nj = 0; nj < 4; ++nj) {
      const int r = rowB + (nj << 4);
      bg[nj] = *(const frag8*)(bp + (r << 6) + (((4 + l4) ^ (r & 7)) << 3));
    }
    asm volatile("s_waitcnt lgkmcnt(0)" ::: "memory");  // all reads of buf[cur] done
    __builtin_amdgcn_s_barrier();                       // ...across all waves
    if (t + 2 < 16) STAGE(cur, t + 2);                  // overwrite freed buffer

    __builtin_amdgcn_s_setprio(1);
#pragma unroll
    for (int mi = 0; mi < 8; ++mi)
#pragma unroll
      for (int nj = 0; nj < 4; ++nj)
        acc[mi][nj] = __builtin_amdgcn_mfma_f32_16x16x32_bf16(
            ag[mi], bg[nj], acc[mi][nj], 0, 0, 0);
    __builtin_amdgcn_s_setprio(0);

    if (t < 14)       asm volatile("s_waitcnt vmcnt(8)" ::: "memory");
    else if (t == 14) asm volatile("s_waitcnt vmcnt(0)" ::: "memory");
    if (t < 15) __builtin_amdgcn_s_barrier();
  }

  // ---- epilogue (16x16 C layout: col = l&15, row = l4*4 + r) ----
  const int m_base = m0 + (wr << 7);
  if (MODE == 0) {
    const int bb16 = (m_base >> 10) << 4;               // batch*16
#pragma unroll
    for (int nj = 0; nj < 4; ++nj) {
      const int n = n0 + (wc << 6) + (nj << 4) + l15;
      const int proj = n >> 10, rem = n & 1023;
      const int h = rem >> 6, d = rem & 63;
      const size_t bh16 = ((size_t)(bb16 + h)) << 16;   // *SEQ*64
      if (proj == 2) {
        // V: write transposed [bh][d][s]; lane holds 4 consecutive s -> sv4
#pragma unroll
        for (int mi = 0; mi < 8; ++mi) {
          const int s0 = (m_base + (mi << 4) + (l4 << 2)) & 1023;
          sv4 pv;
#pragma unroll
          for (int rr = 0; rr < 4; ++rr) pv[rr] = (short)f2bf(acc[mi][nj][rr]);
          *(sv4*)(vto + bh16 + ((size_t)d << 10) + s0) = pv;
        }
      } else {
        unsigned short* dst = (proj == 0) ? qo : ko;
#pragma unroll
        for (int mi = 0; mi < 8; ++mi)
#pragma unroll
          for (int rr = 0; rr < 4; ++rr) {
            const int s = (m_base + (mi << 4) + (l4 << 2) + rr) & 1023;
            dst[bh16 + (size_t)s * 64 + d] = f2bf(acc[mi][nj][rr]);
          }
      }
    }
  } else {
#pragma unroll
    for (int nj = 0; nj < 4; ++nj) {
      const int n = n0 + (wc << 6) + (nj << 4) + l15;
#pragma unroll
      for (int mi = 0; mi < 8; ++mi)
#pragma unroll
        for (int rr = 0; rr < 4; ++rr) {
          const int m = m_base + (mi << 4) + (l4 << 2) + rr;
          fo[(size_t)m * N + n] = acc[mi][nj][rr];
        }
    }
  }
}

// ------------- flash attention, swapped-QK^T 32x32, counted-vmcnt dbuf -------
// Round-4 structure, sched_barrier(0) order-pins removed.
__global__ __launch_bounds__(256, 4) void attn_kernel(
    const unsigned short* __restrict__ q, const unsigned short* __restrict__ k,
    const unsigned short* __restrict__ vt, const float* __restrict__ rel_bias,
    unsigned short* __restrict__ ao) {
  __shared__ unsigned short smem[16384];      // K dbuf [2][4096] | V dbuf [2][4096]
  __shared__ float rb_s[63];
  unsigned short* k_s = smem;                 // 2 x 8 KiB
  unsigned short* v_s = smem + 8192;          // 2 x 8 KiB

  const int bid = blockIdx.x;
  const int xcd = bid & 7, jj = bid >> 3;
  const int bh = xcd * 32 + (jj >> 3), qt = jj & 7;   // 8 q-blocks of a bh -> one XCD
  const int b = bh >> 4, h = bh & 15;
  const int t = threadIdx.x, w = t >> 6, l = t & 63;
  const int l31 = l & 31, hi = l >> 5;

  if (t < 63) rb_s[t] = rel_bias[h * 63 + t] * 1.44269504f;  // pre-scale log2e

  const unsigned short* qg = q + (size_t)bh * (SEQ * 64);
  const unsigned short* kg = k + (size_t)bh * (SEQ * 64);
  const unsigned short* vg = vt + (size_t)bh * (64 * SEQ);

  const int q0 = qt * 128 + w * 32;  // wave's q base (multiple of 32)
  const int qr = q0 >> 5;            // board row of all 32 queries' base

  // Q as B-operand frags: lane holds col q = q0+l31, d-slice s: d = s*16+hi*8+j
  frag8 qf[4];
#pragma unroll
  for (int s = 0; s < 4; ++s)
    qf[s] = *(const frag8*)(qg + (size_t)(q0 + l31) * 64 + s * 16 + hi * 8);

  // stage kt into buffer (4 gl_lds per wave)
  auto STAGE = [&](int buf, int kt) {
#pragma unroll
    for (int i = 0; i < 2; ++i) {
      const int c = i * 256 + t;
      const int row = c >> 3, ch = c & 7;
      const int sw = (ch ^ (row & 7)) << 3;          // pre-swizzled src (shorts)
      const int base = ((i * 256 + w * 64) << 3) + buf * 4096;  // wave-uniform dest
      gl_lds16(kg + (size_t)(kt * 64 + row) * 64 + sw, k_s + base);
      gl_lds16(vg + (size_t)row * SEQ + kt * 64 + sw, v_s + base);
    }
  };
  STAGE(0, 0);

  asm volatile("s_waitcnt lgkmcnt(0)" ::: "memory");  // rb_s write landed
  __builtin_amdgcn_s_barrier();

  // rel_x bias per acc register r: kc = (r&3)+8*(r>>2)+4*hi, qc = l31
  float bx[16];
#pragma unroll
  for (int r = 0; r < 16; ++r) {
    const int kc = (r & 3) + 8 * (r >> 2) + 4 * hi;
    bx[r] = rb_s[kc - l31 + 31];
  }

  float m_run = -1e30f, lsum = 0.f;
  facc16 o0, o1;
#pragma unroll
  for (int i = 0; i < 16; ++i) { o0[i] = 0.f; o1[i] = 0.f; }

  const float C1 = 0.125f * 1.44269504f;  // score scale in exp2 domain

  for (int kt = 0; kt < 16; ++kt) {
    const int p = kt & 1;
    if (kt < 15) {
      STAGE(p ^ 1, kt + 1);
      asm volatile("s_waitcnt vmcnt(4)" ::: "memory");  // kt landed, kt+1 in flight
    } else {
      asm volatile("s_waitcnt vmcnt(0)" ::: "memory");
    }
    __builtin_amdgcn_s_barrier();

    const char* kp = (const char*)(k_s + p * 4096);
    const char* vp = (const char*)(v_s + p * 4096);

    // ---- QK^T: S^T[key, q] per 32-key subtile ----
    facc16 sa[2];
    __builtin_amdgcn_s_setprio(1);
#pragma unroll
    for (int st = 0; st < 2; ++st) {
      facc16 z;
#pragma unroll
      for (int i = 0; i < 16; ++i) z[i] = 0.f;
#pragma unroll
      for (int s = 0; s < 4; ++s) {
        const int row = st * 32 + l31;
        const int byte_off = row * 128 + (((s * 2 + hi) ^ (row & 7)) << 4);
        frag8 kf = *(const frag8*)(kp + byte_off);
        z = __builtin_amdgcn_mfma_f32_32x32x16_bf16(kf, qf[s], z, 0, 0, 0);
      }
      sa[st] = z;
    }
    __builtin_amdgcn_s_setprio(0);

    // ---- bias + online softmax (exp2 domain) ----
    const float by0 = rb_s[kt * 2 + 0 - qr + 31];
    const float by1 = rb_s[kt * 2 + 1 - qr + 31];
    float sc0[16], sc1[16];
#pragma unroll
    for (int r = 0; r < 16; ++r) {
      sc0[r] = __builtin_fmaf(sa[0][r], C1, bx[r]);
      sc1[r] = __builtin_fmaf(sa[1][r], C1, bx[r]);
    }
    float m0 = sc0[0], m1 = sc1[0];
#pragma unroll
    for (int r = 1; r < 16; ++r) { m0 = fmaxf(m0, sc0[r]); m1 = fmaxf(m1, sc1[r]); }
    float tm = fmaxf(m0 + by0, m1 + by1);
    tm = fmaxf(tm, __shfl_xor(tm, 32));
    if (!__all(tm <= m_run + 8.f)) {         // defer-max (T13)
      const float mn = fmaxf(m_run, tm);
      const float corr = __builtin_amdgcn_exp2f(m_run - mn);
      lsum *= corr;
#pragma unroll
      for (int i = 0; i < 16; ++i) { o0[i] *= corr; o1[i] *= corr; }
      m_run = mn;
    }
    const float mb0 = m_run - by0, mb1 = m_run - by1;
    float p0[16], p1[16];
    float ps = 0.f;
#pragma unroll
    for (int r = 0; r < 16; ++r) {
      p0[r] = __builtin_amdgcn_exp2f(sc0[r] - mb0);
      p1[r] = __builtin_amdgcn_exp2f(sc1[r] - mb1);
      ps += p0[r] + p1[r];
    }
    ps += __shfl_xor(ps, 32);
    lsum += ps;

    // ---- repack P -> bf16 B-operand frags (cvt_pk + xor-32 exchange) ----
    unsigned int fw[4][4];
#pragma unroll
    for (int ks = 0; ks < 4; ++ks) {
      const float* pp = (ks < 2) ? p0 : p1;
      const int R0 = (ks & 1) * 8;       // reg base for dest hi=0
      const int R1 = R0 + 4;             // reg base for dest hi=1
      const unsigned int w00 = pk_bf16(pp[R0 + 0], pp[R0 + 1]);
      const unsigned int w01 = pk_bf16(pp[R0 + 2], pp[R0 + 3]);
      const unsigned int w10 = pk_bf16(pp[R1 + 0], pp[R1 + 1]);
      const unsigned int w11 = pk_bf16(pp[R1 + 2], pp[R1 + 3]);
      const unsigned int s0 = hi ? w00 : w10;   // what partner needs
      const unsigned int s1 = hi ? w01 : w11;
      const unsigned int r0 = __shfl_xor((int)s0, 32);
      const unsigned int r1 = __shfl_xor((int)s1, 32);
      fw[ks][0] = hi ? r0 : w00;
      fw[ks][1] = hi ? r1 : w01;
      fw[ks][2] = hi ? w10 : r0;
      fw[ks][3] = hi ? w11 : r1;
    }

    // ---- PV: O^T[d, q] += V^T · P^T ----
    __builtin_amdgcn_s_setprio(1);
#pragma unroll
    for (int ks = 0; ks < 4; ++ks) {
      frag8 pb;
      {
        union { unsigned int u[4]; frag8 f; } cv;
        cv.u[0] = fw[ks][0]; cv.u[1] = fw[ks][1];
        cv.u[2] = fw[ks][2]; cv.u[3] = fw[ks][3];
        pb = cv.f;
      }
      {
        const int row = l31;  // dt = 0
        const int byte_off = row * 128 + (((ks * 2 + hi) ^ (row & 7)) << 4);
        frag8 vf = *(const frag8*)(vp + byte_off);
        o0 = __builtin_amdgcn_mfma_f32_32x32x16_bf16(vf, pb, o0, 0, 0, 0);
      }
      {
        const int row = 32 + l31;  // dt = 1
        const int byte_off = row * 128 + (((ks * 2 + hi) ^ (row & 7)) << 4);
        frag8 vf = *(const frag8*)(vp + byte_off);
        o1 = __builtin_amdgcn_mfma_f32_32x32x16_bf16(vf, pb, o1, 0, 0, 0);
      }
    }
    __builtin_amdgcn_s_setprio(0);

    // all LDS reads of buf p consumed; free it for stage(kt+2)
    asm volatile("s_waitcnt lgkmcnt(0)" ::: "memory");
    __builtin_amdgcn_s_barrier();
  }

  // ---- epilogue: divide, transpose via wave-private LDS (aliased), store ----
  const float inv = __builtin_amdgcn_rcpf(lsum);
  unsigned short (*os)[72] = (unsigned short (*)[72])(smem + w * (32 * 72));
#pragma unroll
  for (int dt = 0; dt < 2; ++dt) {
#pragma unroll
    for (int r = 0; r < 16; r += 2) {
      const int d = (r & 3) + 8 * (r >> 2) + 4 * hi + 32 * dt;
      const float e0 = (dt ? o1[r] : o0[r]) * inv;
      const float e1 = (dt ? o1[r + 1] : o0[r + 1]) * inv;
      *(unsigned int*)&os[l31][d] = pk_bf16(e0, e1);
    }
  }
  asm volatile("s_waitcnt lgkmcnt(0)" ::: "memory");  // wave-private region
#pragma unroll
  for (int i = 0; i < 4; ++i) {
    const int c = i * 64 + l;
    const int qrow = c >> 3, ch = c & 7;
    frag8 ov = *(const frag8*)(&os[qrow][ch * 8]);
    *(frag8*)(ao + ((size_t)(b * SEQ + q0 + qrow) * EMBED + h * 64 + ch * 8)) = ov;
  }
}

// ------------------------------- launcher ------------------------------------
extern "C" void kernel_launch(void* const* d_in, const int* in_sizes, int n_in,
                              void* d_out, int out_size, void* d_ws, size_t ws_size,
                              hipStream_t stream) {
  (void)in_sizes; (void)n_in; (void)out_size; (void)ws_size;
  const float* x  = (const float*)d_in[0];
  const float* Wq = (const float*)d_in[1];
  const float* Wk = (const float*)d_in[2];
  const float* Wv = (const float*)d_in[3];
  const float* Wo = (const float*)d_in[4];
  const float* rb = (const float*)d_in[5];
  float* out = (float*)d_out;

  unsigned short* xb  = (unsigned short*)d_ws;      // 16M elems
  unsigned short* wtq = xb + 16777216;              // 1M each, q|k|v contiguous
  unsigned short* wtk = wtq + 1048576;
  unsigned short* wtv = wtk + 1048576;
  unsigned short* wto = wtv + 1048576;
  unsigned short* qb  = wto + 1048576;              // 16M each
  unsigned short* kb  = qb + 16777216;
  unsigned short* aob = kb + 16777216;
  unsigned short* vtb = aob + 16777216;

  convert_x_kernel<<<4096, 256, 0, stream>>>(x, xb, 16777216 / 8);
  transpose_w_kernel<<<dim3(16, 16, 4), 256, 0, stream>>>(
      Wq, Wk, Wv, Wo, wtq, wtk, wtv, wto);
  gemm256<0><<<768, 512, 0, stream>>>(
      xb, wtq, qb, kb, vtb, nullptr, 3072);
  attn_kernel<<<2048, 256, 0, stream>>>(qb, kb, vtb, rb, aob);
  gemm256<1><<<256, 512, 0, stream>>>(
      aob, wto, nullptr, nullptr, nullptr, out, 1024);
}